// Round 13
// baseline (167.367 us; speedup 1.0000x reference)
//
#include <hip/hip_runtime.h>
#include <hip/hip_bf16.h>
#include <math.h>

#define NB 32
#define NS 4096
#define ND 160
#define ND4 40              // ND in float4
#define NM 16
#define NR 16
#define TPB 64              // tokens per block (16 per wave, 1 MFMA set)
#define NCB (NS / TPB)      // 64 chunks per batch

typedef float  f32x4  __attribute__((ext_vector_type(4)));
typedef short  bf16x8 __attribute__((ext_vector_type(8)));
typedef unsigned int u32x4 __attribute__((ext_vector_type(4)));

// RNE f32 -> bf16, packed pair (lo in low 16, hi in high 16)
__device__ __forceinline__ unsigned bfpair(float lo, float hi) {
    union { float f; unsigned u; } a, c;
    a.f = lo; c.f = hi;
    unsigned ua = (a.u + 0x7FFFu + ((a.u >> 16) & 1u)) >> 16;
    unsigned uc = (c.u + 0x7FFFu + ((c.u >> 16) & 1u)) >> 16;
    return (uc << 16) | (ua & 0xFFFFu);
}

__device__ __forceinline__ bf16x8 asfrag(u32x4 u) {
    union { u32x4 u; bf16x8 h; } x; x.u = u; return x.h;
}

__device__ __forceinline__ bf16x8 mkfrag(unsigned w0, unsigned w1,
                                         unsigned w2, unsigned w3) {
    union { u32x4 u; bf16x8 h; } x;
    x.u = (u32x4){w0, w1, w2, w3};
    return x.h;
}

// ---------------------------------------------------------------------------
// Kernel 0: fold K'/V per batch, emit bf16 MFMA fragments; zero batch counters.
//   K'[m][d] = 0.25*sum_r mem16[m][r]*Wrk[r][d]
//   V [m][d] =      sum_r mem16[m][r]*Wrv[d][r]
// kvfrag[b][0..319]  = kf frags (lane=(lg<<4)|lr holds K'[lr][kb*32+lg*8+j])
// kvfrag[b][320..639]= vf frags (lane32 holds V[lg*8+j][d*16+lr])
// grid = NB, block = 256
// ---------------------------------------------------------------------------
__global__ __launch_bounds__(256) void ulm_fold_kv(
    const float* __restrict__ memory,
    const float* __restrict__ Wrk,     // [NR][ND]
    const float* __restrict__ Wrv,     // [ND][NR]
    u32x4* __restrict__ kvfrag,        // [NB][640]
    unsigned* __restrict__ counters)   // [NB]
{
    __shared__ __align__(16) float sKV[2 * NM * ND];
    __shared__ float sM16[NM * NR];
    const int b = blockIdx.x;
    const int t = threadIdx.x;

    if (t == 0) counters[b] = 0u;      // reset for this call (graph-replay safe)

    sM16[t] = memory[((size_t)b * NM + (t >> 4)) * ND + (t & 15)];
    __syncthreads();

    if (t < ND) {
        float wk[NR], wv[NR];
#pragma unroll
        for (int r = 0; r < NR; ++r) wk[r] = Wrk[r * ND + t];
        const float4* wrv4 = reinterpret_cast<const float4*>(Wrv + t * NR);
#pragma unroll
        for (int j = 0; j < 4; ++j) {
            float4 v = wrv4[j];
            wv[j * 4 + 0] = v.x; wv[j * 4 + 1] = v.y;
            wv[j * 4 + 2] = v.z; wv[j * 4 + 3] = v.w;
        }
#pragma unroll
        for (int m = 0; m < NM; ++m) {
            float aK = 0.f, aV = 0.f;
#pragma unroll
            for (int r = 0; r < NR; ++r) {
                float mv = sM16[m * NR + r];
                aK += mv * wk[r];
                aV += mv * wv[r];
            }
            sKV[m * ND + t]           = aK * 0.25f;   // fold 1/sqrt(R)
            sKV[NM * ND + m * ND + t] = aV;
        }
    }
    __syncthreads();

    u32x4* kb4 = kvfrag + (size_t)b * 640;
    for (int i = t; i < 320; i += 256) {               // kf fragments
        int kb = i >> 6, l = i & 63, lr = l & 15, lg = l >> 4;
        const float* s = &sKV[lr * ND + kb * 32 + lg * 8];
        kb4[i] = (u32x4){bfpair(s[0], s[1]), bfpair(s[2], s[3]),
                         bfpair(s[4], s[5]), bfpair(s[6], s[7])};
    }
    for (int i = t; i < 320; i += 256) {               // vf fragments
        int d = i >> 5, l = i & 31, lr = l & 15, lg = l >> 4;
        const float* s = &sKV[NM * ND + (lg * 8) * ND + d * 16 + lr];
        kb4[320 + i] = (u32x4){bfpair(s[0 * ND], s[1 * ND]),
                               bfpair(s[2 * ND], s[3 * ND]),
                               bfpair(s[4 * ND], s[5 * ND]),
                               bfpair(s[6 * ND], s[7 * ND])};
    }
}

// ---------------------------------------------------------------------------
// Kernel 1: MFMA read path + fused write-path tail (last block per batch).
// Per wave: burst q(10) + kf/vf(15); S^T = mfma(kf,Q^T); softmax in-register;
// iface burst (overlaps softmax/PV); P^T via wave-LDS regroup;
// C^T = mfma(vf,P^T) -> coalesced stores; iface butterfly -> ipart.
// Then: threadfence + per-batch atomic; last block runs i_mean -> i_proj ->
// erase/add -> layernorm for its batch (device-scope fences per G16;
// output bit-deterministic: fixed-order sum over fully-published chunks).
// grid = (NCB=64, NB=32) = 2048 blocks, 256 threads. NO VGPR cap.
// ---------------------------------------------------------------------------
__global__ __launch_bounds__(256) void ulm_read_kernel(
    const float* __restrict__ query,
    const float* __restrict__ iface,
    const float* __restrict__ memory,
    const u32x4* __restrict__ kvfrag,  // [NB][640]
    const float* __restrict__ Wwk,     // [NR][ND]
    const float* __restrict__ Wwe,     // [ND][NR]
    const float* __restrict__ Wwa,     // [ND][NR]
    float* __restrict__ read_out,      // [NB][NS][ND]
    float* __restrict__ new_mem,       // [NB][NM][ND]
    float* __restrict__ ipart,         // [NB][NCB][ND]
    unsigned* __restrict__ counters)   // [NB]
{
    __shared__ unsigned sP[4][16 * 10];   // P^T bf16 pairs, per wave (2.5 KB)
    __shared__ float4 sIred[4 * ND4];     // 2.5 KB
    __shared__ int sLast;
    __shared__ float sIm[ND];
    __shared__ float sIp[NR];
    __shared__ float sOmE[ND];
    __shared__ float sAdd[ND];

    const int t = threadIdx.x;
    const int chunk = blockIdx.x;
    const int b = blockIdx.y;
    const int s0 = chunk * TPB;
    const int w  = t >> 6;             // wave 0..3
    const int l  = t & 63;
    const int lr = l & 15;             // MFMA row/col lane id
    const int lg = l >> 4;             // k-group 0..3

    const size_t base = (size_t)b * NS * ND;
    const int tok = s0 + w * 16 + lr;

    // --- burst 1: q loads (10 float4) ---------------------------------------
    const float4* q4 = reinterpret_cast<const float4*>(query + base);
    float4 qr[10];
#pragma unroll
    for (int kb = 0; kb < 5; ++kb) {
        qr[2*kb]   = q4[(size_t)tok * ND4 + lg * 2 + kb * 8];
        qr[2*kb+1] = q4[(size_t)tok * ND4 + lg * 2 + kb * 8 + 1];
    }

    // --- burst 2: K'/V fragments from L2-hot kvfrag (15 loads) -------------
    const u32x4* kvb = kvfrag + (size_t)b * 640;
    u32x4 kfu[5];
#pragma unroll
    for (int kb = 0; kb < 5; ++kb) kfu[kb] = kvb[kb * 64 + l];
    u32x4 vfu[10];
#pragma unroll
    for (int d = 0; d < 10; ++d)
        vfu[d] = (lg < 2) ? kvb[320 + d * 32 + (l & 31)]
                          : (u32x4){0u, 0u, 0u, 0u};

    // --- S^T = sum_kb mfma(kf[kb], qf[kb]) : D[m=lg*4+r][tok=lr] -----------
    f32x4 D = {0.f, 0.f, 0.f, 0.f};
#pragma unroll
    for (int kb = 0; kb < 5; ++kb) {
        bf16x8 qf = mkfrag(bfpair(qr[2*kb].x,   qr[2*kb].y),
                           bfpair(qr[2*kb].z,   qr[2*kb].w),
                           bfpair(qr[2*kb+1].x, qr[2*kb+1].y),
                           bfpair(qr[2*kb+1].z, qr[2*kb+1].w));
        D = __builtin_amdgcn_mfma_f32_16x16x32_bf16(asfrag(kfu[kb]), qf, D, 0, 0, 0);
    }

    // --- burst 3: iface loads (qr dead; overlap softmax + PV) --------------
    const float4* i4 = reinterpret_cast<const float4*>(iface + base);
    const int l8 = l & 7, g8 = l >> 3;
    const int itok = s0 + w * 16 + g8 * 2;
    float4 iv[10];
#pragma unroll
    for (int j = 0; j < 2; ++j)
#pragma unroll
        for (int k = 0; k < 5; ++k)
            iv[j * 5 + k] = i4[(size_t)(itok + j) * ND4 + l8 + 8 * k];

    // --- softmax over m: in-lane 4 + cross-group xor16, xor32 --------------
    float mx = fmaxf(fmaxf(D[0], D[1]), fmaxf(D[2], D[3]));
    mx = fmaxf(mx, __shfl_xor(mx, 16));
    mx = fmaxf(mx, __shfl_xor(mx, 32));
    float e0 = __expf(D[0] - mx), e1 = __expf(D[1] - mx);
    float e2 = __expf(D[2] - mx), e3 = __expf(D[3] - mx);
    float sm = e0 + e1 + e2 + e3;
    sm += __shfl_xor(sm, 16);
    sm += __shfl_xor(sm, 32);
    float inv = 1.f / sm;
    e0 *= inv; e1 *= inv; e2 *= inv; e3 *= inv;

    // --- P^T regroup via wave-private LDS ----------------------------------
    unsigned* pl = &sP[w][0];
    pl[lr * 10 + lg * 2 + 0] = bfpair(e0, e1);
    pl[lr * 10 + lg * 2 + 1] = bfpair(e2, e3);
    asm volatile("s_waitcnt lgkmcnt(0)" ::: "memory");
    int pb = (lg < 2) ? (lr * 10 + lg * 4) : 0;
    bf16x8 pf = mkfrag(pl[pb], pl[pb + 1], pl[pb + 2], pl[pb + 3]);

    // --- C^T = mfma(vf[d], pf): D2[dcol=d*16+lg*4+r][tok=lr] -> f4 stores ---
    float4* out4 = reinterpret_cast<float4*>(read_out + base);
#pragma unroll
    for (int d = 0; d < 10; ++d) {
        f32x4 D2 = {0.f, 0.f, 0.f, 0.f};
        D2 = __builtin_amdgcn_mfma_f32_16x16x32_bf16(asfrag(vfu[d]), pf, D2, 0, 0, 0);
        out4[(size_t)tok * ND4 + d * 4 + lg] = make_float4(D2[0], D2[1], D2[2], D2[3]);
    }

    // --- iface butterfly: sum this wave's 16 token-rows --------------------
#pragma unroll
    for (int k = 0; k < 5; ++k) {
        float x = iv[k].x + iv[5 + k].x, y = iv[k].y + iv[5 + k].y;
        float z = iv[k].z + iv[5 + k].z, u = iv[k].w + iv[5 + k].w;
#pragma unroll
        for (int off = 8; off <= 32; off <<= 1) {
            x += __shfl_xor(x, off); y += __shfl_xor(y, off);
            z += __shfl_xor(z, off); u += __shfl_xor(u, off);
        }
        if (l < 8) sIred[w * ND4 + k * 8 + l8] = make_float4(x, y, z, u);
    }
    __syncthreads();
    if (t < ND4) {
        float4 a0 = sIred[t], a1 = sIred[ND4 + t];
        float4 a2 = sIred[2 * ND4 + t], a3 = sIred[3 * ND4 + t];
        float4 tot = make_float4(a0.x + a1.x + a2.x + a3.x,
                                 a0.y + a1.y + a2.y + a3.y,
                                 a0.z + a1.z + a2.z + a3.z,
                                 a0.w + a1.w + a2.w + a3.w);
        reinterpret_cast<float4*>(ipart + ((size_t)(b * NCB + chunk)) * ND)[t] = tot;
        __threadfence();   // publish ipart device-wide (cross-XCD, G16)
    }
    __syncthreads();
    if (t == 0) {
        unsigned old = atomicAdd(&counters[b], 1u);   // device-scope
        sLast = (old == NCB - 1);
    }
    __syncthreads();
    if (!sLast) return;

    // ===== fused write path: only the last block of batch b runs this ======
    __threadfence();   // acquire: observe all chunks' ipart

    if (t < ND) {
        float acc = 0.f;
#pragma unroll 8
        for (int c = 0; c < NCB; ++c)
            acc += ipart[((size_t)(b * NCB + c)) * ND + t];
        sIm[t] = acc * (1.0f / NS);
    }
    __syncthreads();

    if (t < NR) {
        float acc = 0.f;
        for (int d = 0; d < ND; ++d) acc += sIm[d] * Wwk[t * ND + d];
        sIp[t] = acc;
    }
    __syncthreads();

    if (t < ND) {
        float e = 0.f, a = 0.f;
#pragma unroll
        for (int r = 0; r < NR; ++r) {
            float ip = sIp[r];
            e += ip * Wwe[t * NR + r];
            a += ip * Wwa[t * NR + r];
        }
        sOmE[t] = 1.0f - 1.0f / (1.0f + __expf(-e));
        sAdd[t] = a;
    }
    __syncthreads();

    // layer norm each of the 16 memory rows; one wave per row
    const int lane = l;
    for (int m = w; m < NM; m += 4) {
        const float* mrow = memory + ((size_t)b * NM + m) * ND;
        float v0 = mrow[lane] * sOmE[lane] + sAdd[lane];
        float v1 = mrow[lane + 64] * sOmE[lane + 64] + sAdd[lane + 64];
        float v2 = 0.f;
        const bool has2 = lane < 32;
        if (has2) v2 = mrow[lane + 128] * sOmE[lane + 128] + sAdd[lane + 128];
        float s  = v0 + v1 + v2;
        float sq = v0 * v0 + v1 * v1 + v2 * v2;
#pragma unroll
        for (int off = 32; off; off >>= 1) {
            s  += __shfl_xor(s, off);
            sq += __shfl_xor(sq, off);
        }
        float mu   = s * (1.0f / ND);
        float var  = sq * (1.0f / ND) - mu * mu;
        float rstd = rsqrtf(var + 1e-5f);
        float* orow = new_mem + ((size_t)b * NM + m) * ND;
        orow[lane]      = (v0 - mu) * rstd;
        orow[lane + 64] = (v1 - mu) * rstd;
        if (has2) orow[lane + 128] = (v2 - mu) * rstd;
    }
}

extern "C" void kernel_launch(void* const* d_in, const int* in_sizes, int n_in,
                              void* d_out, int out_size, void* d_ws, size_t ws_size,
                              hipStream_t stream) {
    const float* query  = (const float*)d_in[0];
    const float* iface  = (const float*)d_in[1];
    const float* memory = (const float*)d_in[2];
    const float* Wrk    = (const float*)d_in[3];
    const float* Wrv    = (const float*)d_in[4];
    const float* Wwk    = (const float*)d_in[5];
    const float* Wwe    = (const float*)d_in[6];
    const float* Wwa    = (const float*)d_in[7];

    float* read_out = (float*)d_out;                        // [32][4096][160]
    float* new_mem  = (float*)d_out + (size_t)NB * NS * ND; // [32][16][160]

    float*    ipart    = (float*)d_ws;                              // 1.31 MB
    u32x4*    kvfrag   = (u32x4*)(ipart + (size_t)NB * NCB * ND);   // 327 KB
    unsigned* counters = (unsigned*)(kvfrag + (size_t)NB * 640);    // 128 B

    ulm_fold_kv<<<NB, 256, 0, stream>>>(memory, Wrk, Wrv, kvfrag, counters);
    dim3 grid1(NCB, NB);
    ulm_read_kernel<<<grid1, 256, 0, stream>>>(query, iface, memory, kvfrag,
                                               Wwk, Wwe, Wwa,
                                               read_out, new_mem, ipart, counters);
}

// Round 14
// 58.187 us; speedup vs baseline: 2.8764x; 2.8764x over previous
//
#include <hip/hip_runtime.h>
#include <hip/hip_bf16.h>
#include <math.h>

#define NB 32
#define NS 4096
#define ND 160
#define ND4 40              // ND in float4
#define NM 16
#define NR 16
#define TPB 64              // tokens per block (16 per wave, 1 MFMA set)
#define NCB (NS / TPB)      // 64 chunks per batch

typedef float  f32x4  __attribute__((ext_vector_type(4)));
typedef short  bf16x8 __attribute__((ext_vector_type(8)));
typedef unsigned int u32x4 __attribute__((ext_vector_type(4)));

__device__ __forceinline__ unsigned short f2bf(float f) {
    union { __hip_bfloat16 b; unsigned short s; } x;
    x.b = __float2bfloat16(f);          // HW RNE on gfx950
    return x.s;
}
__device__ __forceinline__ unsigned bfpair(float lo, float hi) {
    return ((unsigned)f2bf(hi) << 16) | (unsigned)f2bf(lo);
}
__device__ __forceinline__ bf16x8 asfrag(u32x4 u) {
    union { u32x4 u; bf16x8 h; } x; x.u = u; return x.h;
}

// ---------------------------------------------------------------------------
// Kernel 1: factored MFMA read path — NO fold anywhere.
//   G   = Wrk · Q^T          (5 mfma; A = raw Wrk rows, static/L1-hot)
//   S^T = (0.25·M̃) · G       (1 mfma; A = raw mem16 rows; K=16 zero-padded)
//   softmax in-register (2 shfl_xor)
//   H^T = M̃^T · P^T          (1 mfma; = content^T rows 0..15)
//   C^T = Wrv · H^T          (10 mfma; A = raw contiguous Wrv rows)
// Three identical wave-private LDS regroups (G, P, H) move D-layout ->
// B-frag k-layout. R13 lesson: no device fences/atomics. R4/6/9: no VGPR cap.
// grid = (NCB=64, NB=32) = 2048 blocks, 256 threads. 2 launches total.
// ---------------------------------------------------------------------------
__global__ __launch_bounds__(256) void ulm_read_kernel(
    const float* __restrict__ query,
    const float* __restrict__ iface,
    const float* __restrict__ memory,
    const float* __restrict__ Wrk,     // [NR][ND]
    const float* __restrict__ Wrv,     // [ND][NR]
    float* __restrict__ read_out,      // [NB][NS][ND]
    float* __restrict__ ipart)         // [NB][NCB][ND]
{
    __shared__ unsigned sG[4][160];    // 16 rows x stride-10 u32 (bank-safe)
    __shared__ unsigned sPm[4][160];
    __shared__ unsigned sH[4][160];
    __shared__ float4 sIred[4 * ND4];

    const int t = threadIdx.x;
    const int chunk = blockIdx.x;
    const int b = blockIdx.y;
    const int s0 = chunk * TPB;
    const int w  = t >> 6;             // wave 0..3
    const int l  = t & 63;
    const int lr = l & 15;             // MFMA row/col lane id
    const int lg = l >> 4;             // k-group 0..3
    const bool lo2 = (lg < 2);

    const size_t base = (size_t)b * NS * ND;
    const int tok = s0 + w * 16 + lr;

    // --- q loads -> B-frags (B[k=d][col=tok], lane holds Q[lr][kb*32+lg*8+j])
    const float4* q4 = reinterpret_cast<const float4*>(query + base);
    float4 qr[10];
#pragma unroll
    for (int kb = 0; kb < 5; ++kb) {
        qr[2*kb]   = q4[(size_t)tok * ND4 + lg * 2 + kb * 8];
        qr[2*kb+1] = q4[(size_t)tok * ND4 + lg * 2 + kb * 8 + 1];
    }

    // --- Wrk A-frags: A[row=lr][k=kb*32+lg*8+j] = raw Wrk row slices --------
    const float4* wk4 = reinterpret_cast<const float4*>(Wrk);
    u32x4 wf[5];
#pragma unroll
    for (int kb = 0; kb < 5; ++kb) {
        float4 a = wk4[lr * ND4 + kb * 8 + lg * 2];
        float4 c = wk4[lr * ND4 + kb * 8 + lg * 2 + 1];
        wf[kb] = (u32x4){bfpair(a.x, a.y), bfpair(a.z, a.w),
                         bfpair(c.x, c.y), bfpair(c.z, c.w)};
    }

    // --- G = Wrk · Q^T : D[r=lg*4+i][tok=lr] --------------------------------
    f32x4 G = {0.f, 0.f, 0.f, 0.f};
#pragma unroll
    for (int kb = 0; kb < 5; ++kb) {
        u32x4 qf = (u32x4){bfpair(qr[2*kb].x,   qr[2*kb].y),
                           bfpair(qr[2*kb].z,   qr[2*kb].w),
                           bfpair(qr[2*kb+1].x, qr[2*kb+1].y),
                           bfpair(qr[2*kb+1].z, qr[2*kb+1].w)};
        G = __builtin_amdgcn_mfma_f32_16x16x32_bf16(asfrag(wf[kb]), asfrag(qf), G, 0, 0, 0);
    }

    // --- regroup G -> B-frag (B[k=r][col=tok]); k>=16 killed by A zero-pad --
    unsigned* gl = &sG[w][0];
    gl[lr * 10 + lg * 2 + 0] = bfpair(G[0], G[1]);
    gl[lr * 10 + lg * 2 + 1] = bfpair(G[2], G[3]);
    asm volatile("s_waitcnt lgkmcnt(0)" ::: "memory");
    int gb = lo2 ? (lr * 10 + lg * 4) : 0;
    u32x4 gf = (u32x4){gl[gb], gl[gb + 1], gl[gb + 2], gl[gb + 3]};

    // --- A = 0.25 * mem16 rows (K=16 real, lg>=2 zero) ----------------------
    u32x4 mf = (u32x4){0u, 0u, 0u, 0u};
    if (lo2) {
        const float4* m4 = reinterpret_cast<const float4*>(
            memory + ((size_t)b * NM + lr) * ND + lg * 8);
        float4 a = m4[0], c = m4[1];
        mf = (u32x4){bfpair(0.25f * a.x, 0.25f * a.y),
                     bfpair(0.25f * a.z, 0.25f * a.w),
                     bfpair(0.25f * c.x, 0.25f * c.y),
                     bfpair(0.25f * c.z, 0.25f * c.w)};
    }
    f32x4 S = {0.f, 0.f, 0.f, 0.f};
    S = __builtin_amdgcn_mfma_f32_16x16x32_bf16(asfrag(mf), asfrag(gf), S, 0, 0, 0);

    // --- iface burst (q regs dead; latency hides under softmax/PV) ---------
    const float4* i4 = reinterpret_cast<const float4*>(iface + base);
    const int l8 = l & 7, g8 = l >> 3;
    const int itok = s0 + w * 16 + g8 * 2;
    float4 iv[10];
#pragma unroll
    for (int j = 0; j < 2; ++j)
#pragma unroll
        for (int k = 0; k < 5; ++k)
            iv[j * 5 + k] = i4[(size_t)(itok + j) * ND4 + l8 + 8 * k];

    // --- softmax over m: S[m=lg*4+i][tok=lr] --------------------------------
    float mx = fmaxf(fmaxf(S[0], S[1]), fmaxf(S[2], S[3]));
    mx = fmaxf(mx, __shfl_xor(mx, 16));
    mx = fmaxf(mx, __shfl_xor(mx, 32));
    float e0 = __expf(S[0] - mx), e1 = __expf(S[1] - mx);
    float e2 = __expf(S[2] - mx), e3 = __expf(S[3] - mx);
    float sm = e0 + e1 + e2 + e3;
    sm += __shfl_xor(sm, 16);
    sm += __shfl_xor(sm, 32);
    float inv = 1.f / sm;
    e0 *= inv; e1 *= inv; e2 *= inv; e3 *= inv;

    // --- regroup P^T --------------------------------------------------------
    unsigned* pl = &sPm[w][0];
    pl[lr * 10 + lg * 2 + 0] = bfpair(e0, e1);
    pl[lr * 10 + lg * 2 + 1] = bfpair(e2, e3);
    asm volatile("s_waitcnt lgkmcnt(0)" ::: "memory");
    int pb = lo2 ? (lr * 10 + lg * 4) : 0;
    u32x4 pf = (u32x4){pl[pb], pl[pb + 1], pl[pb + 2], pl[pb + 3]};

    // --- H^T = M̃^T · P^T : A[row=lr][k=lg*8+j] = mem16[lg*8+j][lr] ---------
    u32x4 mtf = (u32x4){0u, 0u, 0u, 0u};
    if (lo2) {
        float f0 = memory[((size_t)b * NM + lg * 8 + 0) * ND + lr];
        float f1 = memory[((size_t)b * NM + lg * 8 + 1) * ND + lr];
        float f2 = memory[((size_t)b * NM + lg * 8 + 2) * ND + lr];
        float f3 = memory[((size_t)b * NM + lg * 8 + 3) * ND + lr];
        float f4 = memory[((size_t)b * NM + lg * 8 + 4) * ND + lr];
        float f5 = memory[((size_t)b * NM + lg * 8 + 5) * ND + lr];
        float f6 = memory[((size_t)b * NM + lg * 8 + 6) * ND + lr];
        float f7 = memory[((size_t)b * NM + lg * 8 + 7) * ND + lr];
        mtf = (u32x4){bfpair(f0, f1), bfpair(f2, f3),
                      bfpair(f4, f5), bfpair(f6, f7)};
    }
    f32x4 H = {0.f, 0.f, 0.f, 0.f};
    H = __builtin_amdgcn_mfma_f32_16x16x32_bf16(asfrag(mtf), asfrag(pf), H, 0, 0, 0);

    // --- regroup H^T --------------------------------------------------------
    unsigned* hl = &sH[w][0];
    hl[lr * 10 + lg * 2 + 0] = bfpair(H[0], H[1]);
    hl[lr * 10 + lg * 2 + 1] = bfpair(H[2], H[3]);
    asm volatile("s_waitcnt lgkmcnt(0)" ::: "memory");
    int hb = lo2 ? (lr * 10 + lg * 4) : 0;
    u32x4 hf = (u32x4){hl[hb], hl[hb + 1], hl[hb + 2], hl[hb + 3]};

    // --- C^T = Wrv · H^T : A[row=db*16+lr][k=lg*8+j] = raw Wrv rows ---------
    const float4* wv4 = reinterpret_cast<const float4*>(Wrv);
    float4* out4 = reinterpret_cast<float4*>(read_out + base);
#pragma unroll
    for (int db = 0; db < 10; ++db) {
        u32x4 vf = (u32x4){0u, 0u, 0u, 0u};
        if (lo2) {
            float4 a = wv4[(db * 16 + lr) * 4 + lg * 2];
            float4 c = wv4[(db * 16 + lr) * 4 + lg * 2 + 1];
            vf = (u32x4){bfpair(a.x, a.y), bfpair(a.z, a.w),
                         bfpair(c.x, c.y), bfpair(c.z, c.w)};
        }
        f32x4 C = {0.f, 0.f, 0.f, 0.f};
        C = __builtin_amdgcn_mfma_f32_16x16x32_bf16(asfrag(vf), asfrag(hf), C, 0, 0, 0);
        out4[(size_t)tok * ND4 + db * 4 + lg] = make_float4(C[0], C[1], C[2], C[3]);
    }

    // --- iface butterfly: sum this wave's 16 token-rows --------------------
#pragma unroll
    for (int k = 0; k < 5; ++k) {
        float x = iv[k].x + iv[5 + k].x, y = iv[k].y + iv[5 + k].y;
        float z = iv[k].z + iv[5 + k].z, u = iv[k].w + iv[5 + k].w;
#pragma unroll
        for (int off = 8; off <= 32; off <<= 1) {
            x += __shfl_xor(x, off); y += __shfl_xor(y, off);
            z += __shfl_xor(z, off); u += __shfl_xor(u, off);
        }
        if (l < 8) sIred[w * ND4 + k * 8 + l8] = make_float4(x, y, z, u);
    }
    __syncthreads();
    if (t < ND4) {
        float4 a0 = sIred[t], a1 = sIred[ND4 + t];
        float4 a2 = sIred[2 * ND4 + t], a3 = sIred[3 * ND4 + t];
        float4 tot = make_float4(a0.x + a1.x + a2.x + a3.x,
                                 a0.y + a1.y + a2.y + a3.y,
                                 a0.z + a1.z + a2.z + a3.z,
                                 a0.w + a1.w + a2.w + a3.w);
        reinterpret_cast<float4*>(ipart + ((size_t)(b * NCB + chunk)) * ND)[t] = tot;
    }
}

// ---------------------------------------------------------------------------
// Kernel 2: write path. i_mean -> i_proj -> erase/add -> layer_norm(new_mem)
// grid = NB, block = 256
// ---------------------------------------------------------------------------
__global__ __launch_bounds__(256) void ulm_write_kernel(
    const float* __restrict__ memory,
    const float* __restrict__ Wwk,     // [NR][ND]
    const float* __restrict__ Wwe,     // [ND][NR]
    const float* __restrict__ Wwa,     // [ND][NR]
    const float* __restrict__ ipart,   // [NB][NCB][ND]
    float* __restrict__ new_mem)       // [NB][NM][ND]
{
    __shared__ float sIm[ND];
    __shared__ float sIp[NR];
    __shared__ float sOmE[ND];   // 1 - erase
    __shared__ float sAdd[ND];

    const int b = blockIdx.x;
    const int t = threadIdx.x;

    if (t < ND) {
        float acc = 0.f;
#pragma unroll 8
        for (int c = 0; c < NCB; ++c)
            acc += ipart[((size_t)(b * NCB + c)) * ND + t];
        sIm[t] = acc * (1.0f / NS);
    }
    __syncthreads();

    if (t < NR) {
        float acc = 0.f;
        for (int d = 0; d < ND; ++d) acc += sIm[d] * Wwk[t * ND + d];
        sIp[t] = acc;
    }
    __syncthreads();

    if (t < ND) {
        float e = 0.f, a = 0.f;
#pragma unroll
        for (int r = 0; r < NR; ++r) {
            float ip = sIp[r];
            e += ip * Wwe[t * NR + r];
            a += ip * Wwa[t * NR + r];
        }
        sOmE[t] = 1.0f - 1.0f / (1.0f + __expf(-e));
        sAdd[t] = a;
    }
    __syncthreads();

    // layer norm each of the 16 memory rows; one wave per row
    const int wave = t >> 6, lane = t & 63;
    for (int m = wave; m < NM; m += 4) {
        const float* mrow = memory + ((size_t)b * NM + m) * ND;
        float v0 = mrow[lane] * sOmE[lane] + sAdd[lane];
        float v1 = mrow[lane + 64] * sOmE[lane + 64] + sAdd[lane + 64];
        float v2 = 0.f;
        const bool has2 = lane < 32;
        if (has2) v2 = mrow[lane + 128] * sOmE[lane + 128] + sAdd[lane + 128];
        float s  = v0 + v1 + v2;
        float sq = v0 * v0 + v1 * v1 + v2 * v2;
#pragma unroll
        for (int off = 32; off; off >>= 1) {
            s  += __shfl_xor(s, off);
            sq += __shfl_xor(sq, off);
        }
        float mu   = s * (1.0f / ND);
        float var  = sq * (1.0f / ND) - mu * mu;
        float rstd = rsqrtf(var + 1e-5f);
        float* orow = new_mem + ((size_t)b * NM + m) * ND;
        orow[lane]      = (v0 - mu) * rstd;
        orow[lane + 64] = (v1 - mu) * rstd;
        if (has2) orow[lane + 128] = (v2 - mu) * rstd;
    }
}

extern "C" void kernel_launch(void* const* d_in, const int* in_sizes, int n_in,
                              void* d_out, int out_size, void* d_ws, size_t ws_size,
                              hipStream_t stream) {
    const float* query  = (const float*)d_in[0];
    const float* iface  = (const float*)d_in[1];
    const float* memory = (const float*)d_in[2];
    const float* Wrk    = (const float*)d_in[3];
    const float* Wrv    = (const float*)d_in[4];
    const float* Wwk    = (const float*)d_in[5];
    const float* Wwe    = (const float*)d_in[6];
    const float* Wwa    = (const float*)d_in[7];

    float* read_out = (float*)d_out;                        // [32][4096][160]
    float* new_mem  = (float*)d_out + (size_t)NB * NS * ND; // [32][16][160]
    float* ipart    = (float*)d_ws;                         // NB*NCB*ND f32

    dim3 grid1(NCB, NB);
    ulm_read_kernel<<<grid1, 256, 0, stream>>>(query, iface, memory, Wrk, Wrv,
                                               read_out, ipart);
    ulm_write_kernel<<<NB, 256, 0, stream>>>(memory, Wwk, Wwe, Wwa, ipart, new_mem);
}

// Round 15
// 55.759 us; speedup vs baseline: 3.0016x; 1.0435x over previous
//
#include <hip/hip_runtime.h>
#include <hip/hip_bf16.h>
#include <math.h>

#define NB 32
#define NS 4096
#define ND 160
#define ND4 40              // ND in float4
#define NM 16
#define NR 16
#define TPB 64              // tokens per read block (16 per wave)
#define NCB (NS / TPB)      // 64 read chunks per batch
#define NIC 8               // iface-sum blocks per batch
#define ITOK (NS / NIC)     // 512 tokens per iface block

typedef float  f32x4  __attribute__((ext_vector_type(4)));
typedef short  bf16x8 __attribute__((ext_vector_type(8)));
typedef unsigned int u32x4 __attribute__((ext_vector_type(4)));

__device__ __forceinline__ unsigned short f2bf(float f) {
    union { __hip_bfloat16 b; unsigned short s; } x;
    x.b = __float2bfloat16(f);          // HW RNE on gfx950
    return x.s;
}
__device__ __forceinline__ unsigned bfpair(float lo, float hi) {
    return ((unsigned)f2bf(hi) << 16) | (unsigned)f2bf(lo);
}
__device__ __forceinline__ bf16x8 asfrag(u32x4 u) {
    union { u32x4 u; bf16x8 h; } x; x.u = u; return x.h;
}

// ---------------------------------------------------------------------------
// Kernel 1: two block roles in ONE launch (independent dataflows, no sync):
//  blocks x <  NCB : factored MFMA read path (R14, minus iface work)
//    G = Wrk·Q^T (5 mfma) -> regroup -> S^T = 0.25·M̃·G (1) -> softmax
//    -> P^T regroup -> H^T = M̃^T·P^T (1) -> regroup -> C^T = Wrv·H^T (10)
//  blocks x >= NCB : pure-streaming iface column sums (512 tokens/block)
//    -> the BW sponge that keeps the memory queue full while read blocks
//       sit in their MFMA/regroup latency chains.
//  R13 lesson: no device fences/atomics. R4/6/9: no VGPR cap.
// grid = (NCB+NIC=72, NB=32), 256 threads. 2 launches total.
// ---------------------------------------------------------------------------
__global__ __launch_bounds__(256) void ulm_read_kernel(
    const float* __restrict__ query,
    const float* __restrict__ iface,
    const float* __restrict__ memory,
    const float* __restrict__ Wrk,     // [NR][ND]
    const float* __restrict__ Wrv,     // [ND][NR]
    float* __restrict__ read_out,      // [NB][NS][ND]
    float* __restrict__ ipart)         // [NB][NIC][ND]
{
    __shared__ unsigned sG[4][160];    // read path: stride-10 rows, bank-safe
    __shared__ unsigned sPm[4][160];
    __shared__ unsigned sH[4][160];
    __shared__ float4 sIred[4 * ND4];  // iface path

    const int t = threadIdx.x;
    const int chunk = blockIdx.x;
    const int b = blockIdx.y;
    const int w  = t >> 6;             // wave 0..3
    const int l  = t & 63;
    const size_t base = (size_t)b * NS * ND;

    // ======================= iface-sum blocks ==============================
    if (chunk >= NCB) {
        const int ic = chunk - NCB;
        const float4* i4 = reinterpret_cast<const float4*>(iface + base);
        const int l8 = l & 7, g8 = l >> 3;
        float4 ia[5];
#pragma unroll
        for (int k = 0; k < 5; ++k) ia[k] = make_float4(0.f, 0.f, 0.f, 0.f);
#pragma unroll 4
        for (int p = 0; p < 16; ++p) {
            size_t tk = (size_t)(ic * ITOK + p * 32 + w * 8 + g8);
#pragma unroll
            for (int k = 0; k < 5; ++k) {
                float4 v = i4[tk * ND4 + l8 + 8 * k];
                ia[k].x += v.x; ia[k].y += v.y;
                ia[k].z += v.z; ia[k].w += v.w;
            }
        }
#pragma unroll
        for (int k = 0; k < 5; ++k) {
            float x = ia[k].x, y = ia[k].y, z = ia[k].z, u = ia[k].w;
#pragma unroll
            for (int off = 8; off <= 32; off <<= 1) {
                x += __shfl_xor(x, off); y += __shfl_xor(y, off);
                z += __shfl_xor(z, off); u += __shfl_xor(u, off);
            }
            if (l < 8) sIred[w * ND4 + k * 8 + l8] = make_float4(x, y, z, u);
        }
        __syncthreads();
        if (t < ND4) {
            float4 a0 = sIred[t], a1 = sIred[ND4 + t];
            float4 a2 = sIred[2 * ND4 + t], a3 = sIred[3 * ND4 + t];
            float4 tot = make_float4(a0.x + a1.x + a2.x + a3.x,
                                     a0.y + a1.y + a2.y + a3.y,
                                     a0.z + a1.z + a2.z + a3.z,
                                     a0.w + a1.w + a2.w + a3.w);
            reinterpret_cast<float4*>(ipart + ((size_t)(b * NIC + ic)) * ND)[t] = tot;
        }
        return;
    }

    // ========================= read-path blocks ============================
    const int s0 = chunk * TPB;
    const int lr = l & 15;             // MFMA row/col lane id
    const int lg = l >> 4;             // k-group 0..3
    const bool lo2 = (lg < 2);
    const int tok = s0 + w * 16 + lr;

    // --- q loads -> B-frags (lane holds Q[tok=lr][kb*32+lg*8+j]) -----------
    const float4* q4 = reinterpret_cast<const float4*>(query + base);
    float4 qr[10];
#pragma unroll
    for (int kb = 0; kb < 5; ++kb) {
        qr[2*kb]   = q4[(size_t)tok * ND4 + lg * 2 + kb * 8];
        qr[2*kb+1] = q4[(size_t)tok * ND4 + lg * 2 + kb * 8 + 1];
    }

    // --- Wrk A-frags: raw Wrk row slices (L1-hot) ---------------------------
    const float4* wk4 = reinterpret_cast<const float4*>(Wrk);
    u32x4 wf[5];
#pragma unroll
    for (int kb = 0; kb < 5; ++kb) {
        float4 a = wk4[lr * ND4 + kb * 8 + lg * 2];
        float4 c = wk4[lr * ND4 + kb * 8 + lg * 2 + 1];
        wf[kb] = (u32x4){bfpair(a.x, a.y), bfpair(a.z, a.w),
                         bfpair(c.x, c.y), bfpair(c.z, c.w)};
    }

    // --- G = Wrk · Q^T : D[r=lg*4+i][tok=lr] --------------------------------
    f32x4 G = {0.f, 0.f, 0.f, 0.f};
#pragma unroll
    for (int kb = 0; kb < 5; ++kb) {
        u32x4 qf = (u32x4){bfpair(qr[2*kb].x,   qr[2*kb].y),
                           bfpair(qr[2*kb].z,   qr[2*kb].w),
                           bfpair(qr[2*kb+1].x, qr[2*kb+1].y),
                           bfpair(qr[2*kb+1].z, qr[2*kb+1].w)};
        G = __builtin_amdgcn_mfma_f32_16x16x32_bf16(asfrag(wf[kb]), asfrag(qf), G, 0, 0, 0);
    }

    // --- regroup G -> B-frag; k>=16 killed by A-side zero-pad ---------------
    unsigned* gl = &sG[w][0];
    gl[lr * 10 + lg * 2 + 0] = bfpair(G[0], G[1]);
    gl[lr * 10 + lg * 2 + 1] = bfpair(G[2], G[3]);
    asm volatile("s_waitcnt lgkmcnt(0)" ::: "memory");
    int gb = lo2 ? (lr * 10 + lg * 4) : 0;
    u32x4 gf = (u32x4){gl[gb], gl[gb + 1], gl[gb + 2], gl[gb + 3]};

    // --- S^T = (0.25·M̃) · G --------------------------------------------------
    u32x4 mf = (u32x4){0u, 0u, 0u, 0u};
    if (lo2) {
        const float4* m4 = reinterpret_cast<const float4*>(
            memory + ((size_t)b * NM + lr) * ND + lg * 8);
        float4 a = m4[0], c = m4[1];
        mf = (u32x4){bfpair(0.25f * a.x, 0.25f * a.y),
                     bfpair(0.25f * a.z, 0.25f * a.w),
                     bfpair(0.25f * c.x, 0.25f * c.y),
                     bfpair(0.25f * c.z, 0.25f * c.w)};
    }
    f32x4 S = {0.f, 0.f, 0.f, 0.f};
    S = __builtin_amdgcn_mfma_f32_16x16x32_bf16(asfrag(mf), asfrag(gf), S, 0, 0, 0);

    // --- softmax over m: S[m=lg*4+i][tok=lr] --------------------------------
    float mx = fmaxf(fmaxf(S[0], S[1]), fmaxf(S[2], S[3]));
    mx = fmaxf(mx, __shfl_xor(mx, 16));
    mx = fmaxf(mx, __shfl_xor(mx, 32));
    float e0 = __expf(S[0] - mx), e1 = __expf(S[1] - mx);
    float e2 = __expf(S[2] - mx), e3 = __expf(S[3] - mx);
    float sm = e0 + e1 + e2 + e3;
    sm += __shfl_xor(sm, 16);
    sm += __shfl_xor(sm, 32);
    float inv = 1.f / sm;
    e0 *= inv; e1 *= inv; e2 *= inv; e3 *= inv;

    // --- regroup P^T ---------------------------------------------------------
    unsigned* pl = &sPm[w][0];
    pl[lr * 10 + lg * 2 + 0] = bfpair(e0, e1);
    pl[lr * 10 + lg * 2 + 1] = bfpair(e2, e3);
    asm volatile("s_waitcnt lgkmcnt(0)" ::: "memory");
    int pb = lo2 ? (lr * 10 + lg * 4) : 0;
    u32x4 pf = (u32x4){pl[pb], pl[pb + 1], pl[pb + 2], pl[pb + 3]};

    // --- H^T = M̃^T · P^T -----------------------------------------------------
    u32x4 mtf = (u32x4){0u, 0u, 0u, 0u};
    if (lo2) {
        float f0 = memory[((size_t)b * NM + lg * 8 + 0) * ND + lr];
        float f1 = memory[((size_t)b * NM + lg * 8 + 1) * ND + lr];
        float f2 = memory[((size_t)b * NM + lg * 8 + 2) * ND + lr];
        float f3 = memory[((size_t)b * NM + lg * 8 + 3) * ND + lr];
        float f4 = memory[((size_t)b * NM + lg * 8 + 4) * ND + lr];
        float f5 = memory[((size_t)b * NM + lg * 8 + 5) * ND + lr];
        float f6 = memory[((size_t)b * NM + lg * 8 + 6) * ND + lr];
        float f7 = memory[((size_t)b * NM + lg * 8 + 7) * ND + lr];
        mtf = (u32x4){bfpair(f0, f1), bfpair(f2, f3),
                      bfpair(f4, f5), bfpair(f6, f7)};
    }
    f32x4 H = {0.f, 0.f, 0.f, 0.f};
    H = __builtin_amdgcn_mfma_f32_16x16x32_bf16(asfrag(mtf), asfrag(pf), H, 0, 0, 0);

    // --- regroup H^T ---------------------------------------------------------
    unsigned* hl = &sH[w][0];
    hl[lr * 10 + lg * 2 + 0] = bfpair(H[0], H[1]);
    hl[lr * 10 + lg * 2 + 1] = bfpair(H[2], H[3]);
    asm volatile("s_waitcnt lgkmcnt(0)" ::: "memory");
    int hb = lo2 ? (lr * 10 + lg * 4) : 0;
    u32x4 hf = (u32x4){hl[hb], hl[hb + 1], hl[hb + 2], hl[hb + 3]};

    // --- C^T = Wrv · H^T : raw contiguous Wrv rows -> coalesced stores ------
    const float4* wv4 = reinterpret_cast<const float4*>(Wrv);
    float4* out4 = reinterpret_cast<float4*>(read_out + base);
#pragma unroll
    for (int db = 0; db < 10; ++db) {
        u32x4 vf = (u32x4){0u, 0u, 0u, 0u};
        if (lo2) {
            float4 a = wv4[(db * 16 + lr) * 4 + lg * 2];
            float4 c = wv4[(db * 16 + lr) * 4 + lg * 2 + 1];
            vf = (u32x4){bfpair(a.x, a.y), bfpair(a.z, a.w),
                         bfpair(c.x, c.y), bfpair(c.z, c.w)};
        }
        f32x4 C = {0.f, 0.f, 0.f, 0.f};
        C = __builtin_amdgcn_mfma_f32_16x16x32_bf16(asfrag(vf), asfrag(hf), C, 0, 0, 0);
        out4[(size_t)tok * ND4 + db * 4 + lg] = make_float4(C[0], C[1], C[2], C[3]);
    }
}

// ---------------------------------------------------------------------------
// Kernel 2: write path. i_mean -> i_proj -> erase/add -> layer_norm(new_mem)
// grid = NB, block = 256
// ---------------------------------------------------------------------------
__global__ __launch_bounds__(256) void ulm_write_kernel(
    const float* __restrict__ memory,
    const float* __restrict__ Wwk,     // [NR][ND]
    const float* __restrict__ Wwe,     // [ND][NR]
    const float* __restrict__ Wwa,     // [ND][NR]
    const float* __restrict__ ipart,   // [NB][NIC][ND]
    float* __restrict__ new_mem)       // [NB][NM][ND]
{
    __shared__ float sIm[ND];
    __shared__ float sIp[NR];
    __shared__ float sOmE[ND];   // 1 - erase
    __shared__ float sAdd[ND];

    const int b = blockIdx.x;
    const int t = threadIdx.x;

    if (t < ND) {
        float acc = 0.f;
#pragma unroll
        for (int c = 0; c < NIC; ++c)
            acc += ipart[((size_t)(b * NIC + c)) * ND + t];
        sIm[t] = acc * (1.0f / NS);
    }
    __syncthreads();

    if (t < NR) {
        float acc = 0.f;
        for (int d = 0; d < ND; ++d) acc += sIm[d] * Wwk[t * ND + d];
        sIp[t] = acc;
    }
    __syncthreads();

    if (t < ND) {
        float e = 0.f, a = 0.f;
#pragma unroll
        for (int r = 0; r < NR; ++r) {
            float ip = sIp[r];
            e += ip * Wwe[t * NR + r];
            a += ip * Wwa[t * NR + r];
        }
        sOmE[t] = 1.0f - 1.0f / (1.0f + __expf(-e));
        sAdd[t] = a;
    }
    __syncthreads();

    // layer norm each of the 16 memory rows; one wave per row
    const int wave = t >> 6, lane = t & 63;
    for (int m = wave; m < NM; m += 4) {
        const float* mrow = memory + ((size_t)b * NM + m) * ND;
        float v0 = mrow[lane] * sOmE[lane] + sAdd[lane];
        float v1 = mrow[lane + 64] * sOmE[lane + 64] + sAdd[lane + 64];
        float v2 = 0.f;
        const bool has2 = lane < 32;
        if (has2) v2 = mrow[lane + 128] * sOmE[lane + 128] + sAdd[lane + 128];
        float s  = v0 + v1 + v2;
        float sq = v0 * v0 + v1 * v1 + v2 * v2;
#pragma unroll
        for (int off = 32; off; off >>= 1) {
            s  += __shfl_xor(s, off);
            sq += __shfl_xor(sq, off);
        }
        float mu   = s * (1.0f / ND);
        float var  = sq * (1.0f / ND) - mu * mu;
        float rstd = rsqrtf(var + 1e-5f);
        float* orow = new_mem + ((size_t)b * NM + m) * ND;
        orow[lane]      = (v0 - mu) * rstd;
        orow[lane + 64] = (v1 - mu) * rstd;
        if (has2) orow[lane + 128] = (v2 - mu) * rstd;
    }
}

extern "C" void kernel_launch(void* const* d_in, const int* in_sizes, int n_in,
                              void* d_out, int out_size, void* d_ws, size_t ws_size,
                              hipStream_t stream) {
    const float* query  = (const float*)d_in[0];
    const float* iface  = (const float*)d_in[1];
    const float* memory = (const float*)d_in[2];
    const float* Wrk    = (const float*)d_in[3];
    const float* Wrv    = (const float*)d_in[4];
    const float* Wwk    = (const float*)d_in[5];
    const float* Wwe    = (const float*)d_in[6];
    const float* Wwa    = (const float*)d_in[7];

    float* read_out = (float*)d_out;                        // [32][4096][160]
    float* new_mem  = (float*)d_out + (size_t)NB * NS * ND; // [32][16][160]
    float* ipart    = (float*)d_ws;                         // NB*NIC*ND f32

    dim3 grid1(NCB + NIC, NB);
    ulm_read_kernel<<<grid1, 256, 0, stream>>>(query, iface, memory, Wrk, Wrv,
                                               read_out, ipart);
    ulm_write_kernel<<<NB, 256, 0, stream>>>(memory, Wwk, Wwe, Wwa, ipart, new_mem);
}